// Round 21
// baseline (40.727 us; speedup 1.0000x reference)
//
#include <hip/hip_runtime.h>
#include <hip/hip_bf16.h>
#include <math.h>

#define BB 8
#define NN 2048
#define CC 128
#define DD 128

typedef __attribute__((ext_vector_type(8))) short short8;
typedef __attribute__((ext_vector_type(4))) float f32x4;

static __device__ __forceinline__ unsigned short f2bf(float f) {
    __hip_bfloat16 h = __float2bfloat16(f);
    return *reinterpret_cast<unsigned short*>(&h);
}
static __device__ __forceinline__ float bf2f(unsigned short u) {
    __hip_bfloat16 h = *reinterpret_cast<__hip_bfloat16*>(&u);
    return __bfloat162float(h);
}

// ---------------- Kernel A: fused adj-pack (blocks 0..255) + Wh compute (256..511).
// Outputs WhbT bf16 [b][d][n], f1, EGp = pack(bf16 exp(f2), bf16 exp(0.2 f2)).
#define PACKB 256
__global__ __launch_bounds__(256) void prep_wh_kernel(
    const int* __restrict__ adj, unsigned int* __restrict__ padj,
    const float* __restrict__ x, const float* __restrict__ W,
    const float* __restrict__ a,
    unsigned short* __restrict__ WhbT,
    float* __restrict__ f1, unsigned int* __restrict__ EGp)
{
    __shared__ unsigned short Whs[128 * 136];
    __shared__ unsigned short Wls[128 * 136];
    const int bx  = blockIdx.x;
    const int tid = threadIdx.x;

    if (bx < PACKB) {
        const int wid = bx * 256 + tid;
        #pragma unroll
        for (int rep = 0; rep < 2; ++rep) {
            const int word = wid + rep * 65536;
            const int4* src = (const int4*)adj + (size_t)word * 8;
            unsigned int m = 0;
            #pragma unroll
            for (int k = 0; k < 8; ++k) {
                int4 v = src[k];
                m |= (v.x > 0 ? 1u : 0u) << (k * 4);
                m |= (v.y > 0 ? 1u : 0u) << (k * 4 + 1);
                m |= (v.z > 0 ? 1u : 0u) << (k * 4 + 2);
                m |= (v.w > 0 ? 1u : 0u) << (k * 4 + 3);
            }
            padj[word] = m;
        }
        return;
    }

    const int g  = bx - PACKB;
    const int b  = g & 7;            // XCD-locality: batch b -> XCD b
    const int n0 = (g >> 3) * 64;

    #pragma unroll
    for (int k = 0; k < 16; ++k) {
        const int e   = tid + 256 * k;
        float4 wv = *(const float4*)&W[e * 4];
        const int row = e >> 5;
        const int col = (e & 31) * 4;
        ushort4 hv, lv;
        hv.x = f2bf(wv.x); lv.x = f2bf(wv.x - bf2f(hv.x));
        hv.y = f2bf(wv.y); lv.y = f2bf(wv.y - bf2f(hv.y));
        hv.z = f2bf(wv.z); lv.z = f2bf(wv.z - bf2f(hv.z));
        hv.w = f2bf(wv.w); lv.w = f2bf(wv.w - bf2f(hv.w));
        *(ushort4*)&Whs[row * 136 + col] = hv;
        *(ushort4*)&Wls[row * 136 + col] = lv;
    }
    __syncthreads();

    const int w    = tid >> 6;
    const int lane = tid & 63;
    const int fr   = lane & 15, fk = lane >> 4;
    const int n    = n0 + w * 16 + fr;

    short8 bh[4], bl[4];
    const float* xrow = &x[((size_t)(b * NN) + n) * CC];
    #pragma unroll
    for (int ks = 0; ks < 4; ++ks) {
        float xv[8];
        *(float4*)&xv[0] = *(const float4*)&xrow[(ks * 4 + fk) * 8];
        *(float4*)&xv[4] = *(const float4*)&xrow[(ks * 4 + fk) * 8 + 4];
        #pragma unroll
        for (int e = 0; e < 8; ++e) {
            unsigned short h = f2bf(xv[e]);
            bh[ks][e] = (short)h;
            bl[ks][e] = (short)f2bf(xv[e] - bf2f(h));
        }
    }

    f32x4 acc[8];
    #pragma unroll
    for (int dt = 0; dt < 8; ++dt) acc[dt] = (f32x4){0.f, 0.f, 0.f, 0.f};

    #pragma unroll
    for (int dt = 0; dt < 8; ++dt) {
        #pragma unroll
        for (int ks = 0; ks < 4; ++ks) {
            const int off = (dt * 16 + fr) * 136 + (ks * 4 + fk) * 8;
            short8 aH = *(const short8*)&Whs[off];
            short8 aL = *(const short8*)&Wls[off];
            acc[dt] = __builtin_amdgcn_mfma_f32_16x16x32_bf16(aH, bh[ks], acc[dt], 0, 0, 0);
            acc[dt] = __builtin_amdgcn_mfma_f32_16x16x32_bf16(aH, bl[ks], acc[dt], 0, 0, 0);
            acc[dt] = __builtin_amdgcn_mfma_f32_16x16x32_bf16(aL, bh[ks], acc[dt], 0, 0, 0);
        }
    }

    float p1 = 0.f, p2 = 0.f;
    #pragma unroll
    for (int dt = 0; dt < 8; ++dt) {
        #pragma unroll
        for (int r = 0; r < 4; ++r) {
            const int d = dt * 16 + fk * 4 + r;
            p1 += acc[dt][r] * a[d];
            p2 += acc[dt][r] * a[DD + d];
        }
    }
    p1 += __shfl_xor(p1, 16); p1 += __shfl_xor(p1, 32);
    p2 += __shfl_xor(p2, 16); p2 += __shfl_xor(p2, 32);
    if (fk == 0) {
        f1[b * NN + n] = p1;
        unsigned short e2 = f2bf(__expf(p2));
        unsigned short g2 = f2bf(__expf(0.2f * p2));
        EGp[b * NN + n] = (unsigned int)e2 | ((unsigned int)g2 << 16);
    }

    #pragma unroll
    for (int dt = 0; dt < 8; ++dt) {
        #pragma unroll
        for (int r = 0; r < 4; ++r) {
            const int d = dt * 16 + fk * 4 + r;
            WhbT[((size_t)(b * 128 + d)) * NN + n] = f2bf(acc[dt][r]);
        }
    }
}

// ---------------- Kernel C: single-pass MFMA attention, 32 i x 128 d x ALL j.
// 256 thr / 4 waves, FAT 128-j chunks, SINGLE-buffered tiles (2 barriers/chunk),
// EG packed bf16x2 in LDS. LDS 49.4 KB -> 3 blocks/CU; grid 512 -> >=2 blocks/CU
// give independent barrier domains. XCD-swizzled b = blk&7.
__global__ __launch_bounds__(256) void gat_kernel(
    const unsigned short* __restrict__ WhbT,   // [b][128 d][2048 n] bf16
    const unsigned int* __restrict__ padj,     // [2048][64] bitmask
    const float* __restrict__ f1,
    const unsigned int* __restrict__ EGp,      // packed bf16 (E2,G2) per (b,n)
    float* __restrict__ out)
{
    constexpr int NF = NN / 128;                // 16 fat chunks
    // byte map: [Bs 32K @0 (2 halves x 16K)][Ps 8K @32768 (2 halves x 4K)]
    //           [EGs 8K @40960][Srow 128 @49152][Sred 128 @49280] = 49408 B
    __shared__ __align__(16) unsigned char smem[49408];
    unsigned short* Bs  = (unsigned short*)smem;
    unsigned short* Ps  = (unsigned short*)(smem + 32768);
    unsigned int*   EGs = (unsigned int*)(smem + 40960);
    float* Srow = (float*)(smem + 49152);
    float* Sred = (float*)(smem + 49280);
    float* T    = (float*)smem;                 // 16.9 KB alias after final barrier

    const int tid  = threadIdx.x;
    const int gblk = blockIdx.x;
    const int b    = gblk & 7;                  // XCD-locality
    const int i0   = (gblk >> 3) * 32;

    // stage packed EG row (2048 u32 = 8 KB)
    #pragma unroll
    for (int k = 0; k < NN / 256; ++k)
        EGs[tid + 256 * k] = EGp[b * NN + tid + 256 * k];

    // P role: row = tid>>3 (32 rows), 8 j-elems at pjb*8
    const int prow = tid >> 3;
    const int pjb  = tid & 7;
    const float f1r = f1[b * NN + i0 + prow];
    const float E1r = __expf(f1r);
    const float G1r = __expf(0.2f * f1r);
    const int psw = ((pjb ^ (prow & 7)) << 3);
    const unsigned int* padjRow = padj + (size_t)(i0 + prow) * 64;

    // MFMA role: wave w covers d-cols w*32..w*32+31, i-rows 0..31
    const int w    = tid >> 6;
    const int lane = tid & 63;
    const int fr   = lane & 15;
    const int fk   = lane >> 4;
    f32x4 acc00 = {0.f,0.f,0.f,0.f}, acc01 = {0.f,0.f,0.f,0.f};
    f32x4 acc10 = {0.f,0.f,0.f,0.f}, acc11 = {0.f,0.f,0.f,0.f};
    float s_part = 0.f;

    // B staging per 64-j sub-tile: 1024 x 16B slots, 4 per thread (proven swizzle)
    const size_t wbase = (size_t)b * 128 * NN;
    const int g0 = tid,       gd0 = g0 >> 3, gj0 = (g0 & 7) * 8;
    const int g1 = tid + 256, gd1 = g1 >> 3, gj1 = (g1 & 7) * 8;
    const int g2 = tid + 512, gd2 = g2 >> 3, gj2 = (g2 & 7) * 8;
    const int g3 = tid + 768, gd3 = g3 >> 3, gj3 = (g3 & 7) * 8;
    const int sw0 = gd0 * 64 + ((((g0) & 7) ^ (gd0 & 7)) << 3);
    const int sw1 = gd1 * 64 + ((((g1) & 7) ^ (gd1 & 7)) << 3);
    const int sw2 = gd2 * 64 + ((((g2) & 7) ^ (gd2 & 7)) << 3);
    const int sw3 = gd3 * 64 + ((((g3) & 7) ^ (gd3 & 7)) << 3);

    uint4 brA0, brA1, brA2, brA3, brA4, brA5, brA6, brA7;
    uint4 brB0, brB1, brB2, brB3, brB4, brB5, brB6, brB7;
    unsigned int pwA0, pwA1, pwB0, pwB1;

#define LOADSET(s, c) do {  /* fat chunk c -> sub-chunks 2c, 2c+1 */          \
        br##s##0 = *(const uint4*)&WhbT[wbase + (size_t)gd0 * NN + (2*(c)) * 64 + gj0]; \
        br##s##1 = *(const uint4*)&WhbT[wbase + (size_t)gd1 * NN + (2*(c)) * 64 + gj1]; \
        br##s##2 = *(const uint4*)&WhbT[wbase + (size_t)gd2 * NN + (2*(c)) * 64 + gj2]; \
        br##s##3 = *(const uint4*)&WhbT[wbase + (size_t)gd3 * NN + (2*(c)) * 64 + gj3]; \
        br##s##4 = *(const uint4*)&WhbT[wbase + (size_t)gd0 * NN + (2*(c)+1) * 64 + gj0]; \
        br##s##5 = *(const uint4*)&WhbT[wbase + (size_t)gd1 * NN + (2*(c)+1) * 64 + gj1]; \
        br##s##6 = *(const uint4*)&WhbT[wbase + (size_t)gd2 * NN + (2*(c)+1) * 64 + gj2]; \
        br##s##7 = *(const uint4*)&WhbT[wbase + (size_t)gd3 * NN + (2*(c)+1) * 64 + gj3]; \
        pw##s##0 = padjRow[(2*(c)) * 2 + (pjb >> 2)];                        \
        pw##s##1 = padjRow[(2*(c)+1) * 2 + (pjb >> 2)];                      \
    } while (0)

#define PHALF(pwv, bX0, bX1, bX2, bX3, sc, h) do {                           \
        uint4 ea = *(const uint4*)&EGs[(sc) * 64 + pjb * 8];                 \
        uint4 eb = *(const uint4*)&EGs[(sc) * 64 + pjb * 8 + 4];             \
        unsigned int egw[8];                                                 \
        *(uint4*)&egw[0] = ea; *(uint4*)&egw[4] = eb;                        \
        unsigned int pbits = ((pwv) >> ((pjb & 3) << 3)) & 0xffu;            \
        unsigned short pks[8];                                               \
        float ssum = 0.f;                                                    \
        _Pragma("unroll")                                                    \
        for (int e = 0; e < 8; ++e) {                                        \
            float e2 = bf2f((unsigned short)(egw[e] & 0xffffu));             \
            float g2 = bf2f((unsigned short)(egw[e] >> 16));                 \
            float mv = E1r * e2;                                             \
            float gg = G1r * g2;                                             \
            float wv = fmaxf(mv, gg);                                        \
            wv = ((pbits >> e) & 1u) ? wv : 0.f;                             \
            unsigned short bw = f2bf(wv);                                    \
            pks[e] = bw;                                                     \
            ssum += bf2f(bw);                                                \
        }                                                                    \
        s_part += ssum;                                                      \
        *(uint4*)&Bs[(h) * 8192 + sw0] = bX0;                                \
        *(uint4*)&Bs[(h) * 8192 + sw1] = bX1;                                \
        *(uint4*)&Bs[(h) * 8192 + sw2] = bX2;                                \
        *(uint4*)&Bs[(h) * 8192 + sw3] = bX3;                                \
        uint4 pv;                                                            \
        pv.x = (unsigned int)pks[0] | ((unsigned int)pks[1] << 16);          \
        pv.y = (unsigned int)pks[2] | ((unsigned int)pks[3] << 16);          \
        pv.z = (unsigned int)pks[4] | ((unsigned int)pks[5] << 16);          \
        pv.w = (unsigned int)pks[6] | ((unsigned int)pks[7] << 16);          \
        *(uint4*)&Ps[(h) * 2048 + prow * 64 + psw] = pv;                     \
    } while (0)

#define PSTAGE(s, c) do {                                                    \
        PHALF(pw##s##0, br##s##0, br##s##1, br##s##2, br##s##3, 2*(c),     0); \
        PHALF(pw##s##1, br##s##4, br##s##5, br##s##6, br##s##7, 2*(c) + 1, 1); \
    } while (0)

#define MFMAC() do {                                                         \
        __builtin_amdgcn_s_setprio(1);                                       \
        _Pragma("unroll")                                                    \
        for (int h = 0; h < 2; ++h) {                                        \
            _Pragma("unroll")                                                \
            for (int ks = 0; ks < 2; ++ks) {                                 \
                const int jbl = ks * 4 + fk;                                 \
                const int sb  = ((jbl ^ (fr & 7)) << 3);                     \
                short8 aF0 = *(const short8*)&Ps[h * 2048 + fr * 64 + sb];   \
                short8 aF1 = *(const short8*)&Ps[h * 2048 + (16 + fr) * 64 + sb]; \
                short8 bF0 = *(const short8*)&Bs[h * 8192 + (w * 32 + fr) * 64 + sb]; \
                short8 bF1 = *(const short8*)&Bs[h * 8192 + (w * 32 + 16 + fr) * 64 + sb]; \
                acc00 = __builtin_amdgcn_mfma_f32_16x16x32_bf16(aF0, bF0, acc00, 0, 0, 0); \
                acc01 = __builtin_amdgcn_mfma_f32_16x16x32_bf16(aF0, bF1, acc01, 0, 0, 0); \
                acc10 = __builtin_amdgcn_mfma_f32_16x16x32_bf16(aF1, bF0, acc10, 0, 0, 0); \
                acc11 = __builtin_amdgcn_mfma_f32_16x16x32_bf16(aF1, bF1, acc11, 0, 0, 0); \
            }                                                                \
        }                                                                    \
        __builtin_amdgcn_s_setprio(0);                                       \
    } while (0)

    // prologue: prefetch fat chunks 0 and 1 into the two register sets
    LOADSET(A, 0);
    LOADSET(B, 1);
    __syncthreads();                 // EGs ready

    #pragma unroll 1
    for (int cc = 0; cc < NF; cc += 2) {
        PSTAGE(A, cc);                       // tiles for chunk cc
        if (cc + 2 < NF) LOADSET(A, cc + 2); // refill set A
        __syncthreads();                     // tiles ready
        MFMAC();
        __syncthreads();                     // reads done; safe to overwrite
        PSTAGE(B, cc + 1);
        if (cc + 3 < NF) LOADSET(B, cc + 3);
        __syncthreads();
        MFMAC();
        __syncthreads();
    }

#undef LOADSET
#undef PHALF
#undef PSTAGE
#undef MFMAC

    // row-sum: 8 threads per row
    {
        float v = s_part;
        v += __shfl_xor(v, 1); v += __shfl_xor(v, 2); v += __shfl_xor(v, 4);
        if (pjb == 0) Srow[prow] = v;
    }
    __syncthreads();
    if (tid < 32) Sred[tid] = 1.0f / Srow[tid];
    __syncthreads();

    // normalize + elu into T (aliases tile buffers; all MFMA reads done)
    #pragma unroll
    for (int it = 0; it < 2; ++it) {
        #pragma unroll
        for (int dt = 0; dt < 2; ++dt) {
            f32x4 av = (it == 0) ? (dt == 0 ? acc00 : acc01)
                                 : (dt == 0 ? acc10 : acc11);
            #pragma unroll
            for (int r = 0; r < 4; ++r) {
                const int i = it * 16 + fk * 4 + r;
                const int d = w * 32 + dt * 16 + fr;
                float hv = av[r] * Sred[i];
                hv = (hv > 0.f) ? hv : expm1f(hv);
                T[i * 132 + d] = hv;
            }
        }
    }
    __syncthreads();

    #pragma unroll
    for (int k = 0; k < 4; ++k) {
        const int g   = tid + 256 * k;     // 1024 float4 = 32 x 128
        const int row = g >> 5;
        const int d4  = (g & 31) * 4;
        float4 h = *(const float4*)&T[row * 132 + d4];
        *(float4*)&out[((size_t)(b * NN) + i0 + row) * DD + d4] = h;
    }
}

extern "C" void kernel_launch(void* const* d_in, const int* in_sizes, int n_in,
                              void* d_out, int out_size, void* d_ws, size_t ws_size,
                              hipStream_t stream) {
    const float* x   = (const float*)d_in[0];
    const int*   adj = (const int*)d_in[1];
    const float* W   = (const float*)d_in[2];
    const float* a   = (const float*)d_in[3];
    float* out = (float*)d_out;

    char* p = (char*)d_ws;
    unsigned short* WhbT = (unsigned short*)p; p += (size_t)BB * NN * DD * 2;  // 4 MB
    float* f1 = (float*)p;                p += (size_t)BB * NN * 4;            // 64 KB
    unsigned int* EGp = (unsigned int*)p; p += (size_t)BB * NN * 4;            // 64 KB
    unsigned int* padj = (unsigned int*)p; p += (size_t)NN * 64 * 4;           // 512 KB

    prep_wh_kernel<<<PACKB + (NN / 64) * BB, 256, 0, stream>>>(
        adj, padj, x, W, a, WhbT, f1, EGp);
    gat_kernel<<<(NN / 32) * BB, 256, 0, stream>>>(
        WhbT, padj, f1, EGp, out);
}

// Round 22
// 35.125 us; speedup vs baseline: 1.1595x; 1.1595x over previous
//
#include <hip/hip_runtime.h>
#include <hip/hip_bf16.h>
#include <math.h>

#define BB 8
#define NN 2048
#define CC 128
#define DD 128

typedef __attribute__((ext_vector_type(8))) short short8;
typedef __attribute__((ext_vector_type(4))) float f32x4;

static __device__ __forceinline__ unsigned short f2bf(float f) {
    __hip_bfloat16 h = __float2bfloat16(f);
    return *reinterpret_cast<unsigned short*>(&h);
}
static __device__ __forceinline__ float bf2f(unsigned short u) {
    __hip_bfloat16 h = *reinterpret_cast<__hip_bfloat16*>(&u);
    return __bfloat162float(h);
}
// LDS-only barrier: drain DS ops, keep global loads in flight (HK/m201 pattern)
static __device__ __forceinline__ void lds_barrier() {
    asm volatile("s_waitcnt lgkmcnt(0)" ::: "memory");
    __builtin_amdgcn_s_barrier();
}

// ---------------- Kernel A: fused adj-pack (blocks 0..255) + Wh compute (256..511).
#define PACKB 256
__global__ __launch_bounds__(256) void prep_wh_kernel(
    const int* __restrict__ adj, unsigned int* __restrict__ padj,
    const float* __restrict__ x, const float* __restrict__ W,
    const float* __restrict__ a,
    unsigned short* __restrict__ WhbT,
    float* __restrict__ f1, float* __restrict__ E2g, float* __restrict__ G2g)
{
    __shared__ unsigned short Whs[128 * 136];
    __shared__ unsigned short Wls[128 * 136];
    const int bx  = blockIdx.x;
    const int tid = threadIdx.x;

    if (bx < PACKB) {
        const int wid = bx * 256 + tid;
        #pragma unroll
        for (int rep = 0; rep < 2; ++rep) {
            const int word = wid + rep * 65536;
            const int4* src = (const int4*)adj + (size_t)word * 8;
            unsigned int m = 0;
            #pragma unroll
            for (int k = 0; k < 8; ++k) {
                int4 v = src[k];
                m |= (v.x > 0 ? 1u : 0u) << (k * 4);
                m |= (v.y > 0 ? 1u : 0u) << (k * 4 + 1);
                m |= (v.z > 0 ? 1u : 0u) << (k * 4 + 2);
                m |= (v.w > 0 ? 1u : 0u) << (k * 4 + 3);
            }
            padj[word] = m;
        }
        return;
    }

    const int g  = bx - PACKB;
    const int b  = g & 7;            // XCD-locality: batch b -> XCD b
    const int n0 = (g >> 3) * 64;

    #pragma unroll
    for (int k = 0; k < 16; ++k) {
        const int e   = tid + 256 * k;
        float4 wv = *(const float4*)&W[e * 4];
        const int row = e >> 5;
        const int col = (e & 31) * 4;
        ushort4 hv, lv;
        hv.x = f2bf(wv.x); lv.x = f2bf(wv.x - bf2f(hv.x));
        hv.y = f2bf(wv.y); lv.y = f2bf(wv.y - bf2f(hv.y));
        hv.z = f2bf(wv.z); lv.z = f2bf(wv.z - bf2f(hv.z));
        hv.w = f2bf(wv.w); lv.w = f2bf(wv.w - bf2f(hv.w));
        *(ushort4*)&Whs[row * 136 + col] = hv;
        *(ushort4*)&Wls[row * 136 + col] = lv;
    }
    __syncthreads();

    const int w    = tid >> 6;
    const int lane = tid & 63;
    const int fr   = lane & 15, fk = lane >> 4;
    const int n    = n0 + w * 16 + fr;

    short8 bh[4], bl[4];
    const float* xrow = &x[((size_t)(b * NN) + n) * CC];
    #pragma unroll
    for (int ks = 0; ks < 4; ++ks) {
        float xv[8];
        *(float4*)&xv[0] = *(const float4*)&xrow[(ks * 4 + fk) * 8];
        *(float4*)&xv[4] = *(const float4*)&xrow[(ks * 4 + fk) * 8 + 4];
        #pragma unroll
        for (int e = 0; e < 8; ++e) {
            unsigned short h = f2bf(xv[e]);
            bh[ks][e] = (short)h;
            bl[ks][e] = (short)f2bf(xv[e] - bf2f(h));
        }
    }

    f32x4 acc[8];
    #pragma unroll
    for (int dt = 0; dt < 8; ++dt) acc[dt] = (f32x4){0.f, 0.f, 0.f, 0.f};

    #pragma unroll
    for (int dt = 0; dt < 8; ++dt) {
        #pragma unroll
        for (int ks = 0; ks < 4; ++ks) {
            const int off = (dt * 16 + fr) * 136 + (ks * 4 + fk) * 8;
            short8 aH = *(const short8*)&Whs[off];
            short8 aL = *(const short8*)&Wls[off];
            acc[dt] = __builtin_amdgcn_mfma_f32_16x16x32_bf16(aH, bh[ks], acc[dt], 0, 0, 0);
            acc[dt] = __builtin_amdgcn_mfma_f32_16x16x32_bf16(aH, bl[ks], acc[dt], 0, 0, 0);
            acc[dt] = __builtin_amdgcn_mfma_f32_16x16x32_bf16(aL, bh[ks], acc[dt], 0, 0, 0);
        }
    }

    float p1 = 0.f, p2 = 0.f;
    #pragma unroll
    for (int dt = 0; dt < 8; ++dt) {
        #pragma unroll
        for (int r = 0; r < 4; ++r) {
            const int d = dt * 16 + fk * 4 + r;
            p1 += acc[dt][r] * a[d];
            p2 += acc[dt][r] * a[DD + d];
        }
    }
    p1 += __shfl_xor(p1, 16); p1 += __shfl_xor(p1, 32);
    p2 += __shfl_xor(p2, 16); p2 += __shfl_xor(p2, 32);
    if (fk == 0) {
        f1[b * NN + n]  = p1;
        E2g[b * NN + n] = __expf(p2);
        G2g[b * NN + n] = __expf(0.2f * p2);
    }

    #pragma unroll
    for (int dt = 0; dt < 8; ++dt) {
        #pragma unroll
        for (int r = 0; r < 4; ++r) {
            const int d = dt * 16 + fk * 4 + r;
            WhbT[((size_t)(b * 128 + d)) * NN + n] = f2bf(acc[dt][r]);
        }
    }
}

// ---------------- Kernel C: single-pass MFMA attention, 64 i x 128 d x ALL j.
// R20 structure (fat 128-j chunks, dbuf, 18 barriers) with LDS-ONLY barriers in
// the main loop: global prefetch stays in flight across phases (no vmcnt drain).
__global__ __launch_bounds__(512) void gat_kernel(
    const unsigned short* __restrict__ WhbT,   // [b][128 d][2048 n] bf16
    const unsigned int* __restrict__ padj,     // [2048][64] bitmask
    const float* __restrict__ f1,
    const float* __restrict__ E2g, const float* __restrict__ G2g,
    float* __restrict__ out)
{
    constexpr int NF = NN / 128;                // 16 fat chunks
    // byte map: [Bs0 32K @0][Bs1 32K @32768][Ps0 16K @65536][Ps1 16K @81920]
    //           [E2s 8K @98304][G2s 8K @106496][Srow 256 @114688][Sred 256 @114944]
    __shared__ __align__(16) unsigned char smem[115200];
    unsigned short* Bs0 = (unsigned short*)smem;                 // 2 halves x 16 KB
    unsigned short* Bs1 = (unsigned short*)(smem + 32768);
    unsigned short* Ps0 = (unsigned short*)(smem + 65536);       // 2 halves x 8 KB
    unsigned short* Ps1 = (unsigned short*)(smem + 81920);
    float* E2s  = (float*)(smem + 98304);
    float* G2s  = (float*)(smem + 106496);
    float* Srow = (float*)(smem + 114688);
    float* Sred = (float*)(smem + 114944);
    float* T    = (float*)smem;                 // 33.8 KB alias after final barrier

    const int tid  = threadIdx.x;
    const int gblk = blockIdx.x;
    const int b    = gblk & 7;                  // XCD-locality
    const int i0   = (gblk >> 3) * 64;

    #pragma unroll
    for (int k = 0; k < NN / 512; ++k) {
        E2s[tid + 512 * k] = E2g[b * NN + tid + 512 * k];
        G2s[tid + 512 * k] = G2g[b * NN + tid + 512 * k];
    }

    // P role: row = tid>>3 (64 rows), 8 j-elems per half at pjb*8
    const int prow = tid >> 3;
    const int pjb  = tid & 7;
    const float f1r = f1[b * NN + i0 + prow];
    const float E1r = __expf(f1r);
    const float G1r = __expf(0.2f * f1r);
    const int psw = ((pjb ^ (prow & 7)) << 3);
    const unsigned int* padjRow = padj + (size_t)(i0 + prow) * 64;

    // MFMA role: wave (wr,wc) in 2x4
    const int w    = tid >> 6;
    const int wr   = w >> 2, wc = w & 3;
    const int lane = tid & 63;
    const int fr   = lane & 15;
    const int fk   = lane >> 4;
    f32x4 acc00 = {0.f,0.f,0.f,0.f}, acc01 = {0.f,0.f,0.f,0.f};
    f32x4 acc10 = {0.f,0.f,0.f,0.f}, acc11 = {0.f,0.f,0.f,0.f};
    float s_part = 0.f;

    // B staging per 64-j sub-tile: 1024 x 16B slots, 2 per thread (proven swizzle)
    const size_t wbase = (size_t)b * 128 * NN;
    const int g0 = tid,       gd0 = g0 >> 3, gj0 = (g0 & 7) * 8;
    const int g1 = tid + 512, gd1 = g1 >> 3, gj1 = (g1 & 7) * 8;
    const int sw0 = gd0 * 64 + ((((g0) & 7) ^ (gd0 & 7)) << 3);
    const int sw1 = gd1 * 64 + ((((g1) & 7) ^ (gd1 & 7)) << 3);

    uint4 brA0, brA1, brA2, brA3, brB0, brB1, brB2, brB3;
    unsigned int pwA0, pwA1, pwB0, pwB1;

#define LOADSET(s, c) do {  /* c = fat-chunk index; sub-chunks 2c, 2c+1 */    \
        br##s##0 = *(const uint4*)&WhbT[wbase + (size_t)gd0 * NN + (2*(c)) * 64 + gj0]; \
        br##s##1 = *(const uint4*)&WhbT[wbase + (size_t)gd1 * NN + (2*(c)) * 64 + gj1]; \
        br##s##2 = *(const uint4*)&WhbT[wbase + (size_t)gd0 * NN + (2*(c)+1) * 64 + gj0]; \
        br##s##3 = *(const uint4*)&WhbT[wbase + (size_t)gd1 * NN + (2*(c)+1) * 64 + gj1]; \
        pw##s##0 = padjRow[(2*(c)) * 2 + (pjb >> 2)];                        \
        pw##s##1 = padjRow[(2*(c)+1) * 2 + (pjb >> 2)];                      \
    } while (0)

#define PHALF(Bsb, Psb, pwv, brX, brY, sc, h) do {                           \
        float4 eA = *(const float4*)&E2s[(sc) * 64 + pjb * 8];               \
        float4 eB = *(const float4*)&E2s[(sc) * 64 + pjb * 8 + 4];           \
        float4 gA = *(const float4*)&G2s[(sc) * 64 + pjb * 8];               \
        float4 gB = *(const float4*)&G2s[(sc) * 64 + pjb * 8 + 4];           \
        float ev[8], gv[8];                                                  \
        *(float4*)&ev[0] = eA; *(float4*)&ev[4] = eB;                        \
        *(float4*)&gv[0] = gA; *(float4*)&gv[4] = gB;                        \
        unsigned int pbits = ((pwv) >> ((pjb & 3) << 3)) & 0xffu;            \
        unsigned short pks[8];                                               \
        float ssum = 0.f;                                                    \
        _Pragma("unroll")                                                    \
        for (int e = 0; e < 8; ++e) {                                        \
            float mv = E1r * ev[e];                                          \
            float gg = G1r * gv[e];                                          \
            float wv = fmaxf(mv, gg);                                        \
            wv = ((pbits >> e) & 1u) ? wv : 0.f;                             \
            unsigned short bw = f2bf(wv);                                    \
            pks[e] = bw;                                                     \
            ssum += bf2f(bw);                                                \
        }                                                                    \
        s_part += ssum;                                                      \
        *(uint4*)&(Bsb)[(h) * 8192 + sw0] = brX;                             \
        *(uint4*)&(Bsb)[(h) * 8192 + sw1] = brY;                             \
        uint4 pv;                                                            \
        pv.x = (unsigned int)pks[0] | ((unsigned int)pks[1] << 16);          \
        pv.y = (unsigned int)pks[2] | ((unsigned int)pks[3] << 16);          \
        pv.z = (unsigned int)pks[4] | ((unsigned int)pks[5] << 16);          \
        pv.w = (unsigned int)pks[6] | ((unsigned int)pks[7] << 16);          \
        *(uint4*)&(Psb)[(h) * 4096 + prow * 64 + psw] = pv;                  \
    } while (0)

#define PSTAGE(Bsb, Psb, s, c) do {                                          \
        PHALF(Bsb, Psb, pw##s##0, br##s##0, br##s##1, 2*(c),     0);         \
        PHALF(Bsb, Psb, pw##s##1, br##s##2, br##s##3, 2*(c) + 1, 1);         \
    } while (0)

#define MHALF(Bsb, Psb, h) do {                                              \
        _Pragma("unroll")                                                    \
        for (int ks = 0; ks < 2; ++ks) {                                     \
            const int jbl = ks * 4 + fk;                                     \
            const int sb  = ((jbl ^ (fr & 7)) << 3);                         \
            short8 aF0 = *(const short8*)&(Psb)[(h) * 4096 + (wr * 32 + fr) * 64 + sb]; \
            short8 aF1 = *(const short8*)&(Psb)[(h) * 4096 + (wr * 32 + 16 + fr) * 64 + sb]; \
            short8 bF0 = *(const short8*)&(Bsb)[(h) * 8192 + (wc * 32 + fr) * 64 + sb]; \
            short8 bF1 = *(const short8*)&(Bsb)[(h) * 8192 + (wc * 32 + 16 + fr) * 64 + sb]; \
            acc00 = __builtin_amdgcn_mfma_f32_16x16x32_bf16(aF0, bF0, acc00, 0, 0, 0); \
            acc01 = __builtin_amdgcn_mfma_f32_16x16x32_bf16(aF0, bF1, acc01, 0, 0, 0); \
            acc10 = __builtin_amdgcn_mfma_f32_16x16x32_bf16(aF1, bF0, acc10, 0, 0, 0); \
            acc11 = __builtin_amdgcn_mfma_f32_16x16x32_bf16(aF1, bF1, acc11, 0, 0, 0); \
        }                                                                    \
    } while (0)

#define MFMAC(Bsb, Psb) do {                                                 \
        __builtin_amdgcn_s_setprio(1);                                       \
        MHALF(Bsb, Psb, 0);                                                  \
        MHALF(Bsb, Psb, 1);                                                  \
        __builtin_amdgcn_s_setprio(0);                                       \
    } while (0)

    // prologue: fat chunk 0 -> buf0; prefetch fat chunk 1
    LOADSET(A, 0);
    lds_barrier();                   // E2s/G2s ds_writes drained
    PSTAGE(Bs0, Ps0, A, 0);
    LOADSET(B, 1);
    lds_barrier();                   // buf0 tiles drained; B-loads stay in flight

    #pragma unroll 1
    for (int cc = 0; cc < NF; cc += 2) {
        PSTAGE(Bs1, Ps1, B, cc + 1);
        if (cc + 2 < NF) LOADSET(A, cc + 2);
        MFMAC(Bs0, Ps0);
        lds_barrier();
        if (cc + 2 < NF) PSTAGE(Bs0, Ps0, A, cc + 2);
        if (cc + 3 < NF) LOADSET(B, cc + 3);
        MFMAC(Bs1, Ps1);
        lds_barrier();
    }

#undef LOADSET
#undef PHALF
#undef PSTAGE
#undef MHALF
#undef MFMAC

    // row-sum: 8 threads per row
    {
        float v = s_part;
        v += __shfl_xor(v, 1); v += __shfl_xor(v, 2); v += __shfl_xor(v, 4);
        if (pjb == 0) Srow[prow] = v;
    }
    __syncthreads();
    if (tid < 64) Sred[tid] = 1.0f / Srow[tid];
    __syncthreads();

    // normalize + elu into T (aliases tile buffers; all MFMA reads done)
    #pragma unroll
    for (int it = 0; it < 2; ++it) {
        #pragma unroll
        for (int dt = 0; dt < 2; ++dt) {
            f32x4 av = (it == 0) ? (dt == 0 ? acc00 : acc01)
                                 : (dt == 0 ? acc10 : acc11);
            #pragma unroll
            for (int r = 0; r < 4; ++r) {
                const int i = wr * 32 + it * 16 + fk * 4 + r;
                const int d = wc * 32 + dt * 16 + fr;
                float hv = av[r] * Sred[i];
                hv = (hv > 0.f) ? hv : expm1f(hv);
                T[i * 132 + d] = hv;
            }
        }
    }
    __syncthreads();

    #pragma unroll
    for (int k = 0; k < 4; ++k) {
        const int g   = tid + 512 * k;     // 2048 float4 = 64 x 128
        const int row = g >> 5;
        const int d4  = (g & 31) * 4;
        float4 h = *(const float4*)&T[row * 132 + d4];
        *(float4*)&out[((size_t)(b * NN) + i0 + row) * DD + d4] = h;
    }
}

extern "C" void kernel_launch(void* const* d_in, const int* in_sizes, int n_in,
                              void* d_out, int out_size, void* d_ws, size_t ws_size,
                              hipStream_t stream) {
    const float* x   = (const float*)d_in[0];
    const int*   adj = (const int*)d_in[1];
    const float* W   = (const float*)d_in[2];
    const float* a   = (const float*)d_in[3];
    float* out = (float*)d_out;

    char* p = (char*)d_ws;
    unsigned short* WhbT = (unsigned short*)p; p += (size_t)BB * NN * DD * 2;  // 4 MB
    float* f1  = (float*)p; p += (size_t)BB * NN * 4;                          // 64 KB
    float* E2g = (float*)p; p += (size_t)BB * NN * 4;                          // 64 KB
    float* G2g = (float*)p; p += (size_t)BB * NN * 4;                          // 64 KB
    unsigned int* padj = (unsigned int*)p;    p += (size_t)NN * 64 * 4;        // 512 KB

    prep_wh_kernel<<<PACKB + (NN / 64) * BB, 256, 0, stream>>>(
        adj, padj, x, W, a, WhbT, f1, E2g, G2g);
    gat_kernel<<<(NN / 64) * BB, 512, 0, stream>>>(
        WhbT, padj, f1, E2g, G2g, out);
}